// Round 7
// baseline (391.604 us; speedup 1.0000x reference)
//
#include <hip/hip_runtime.h>
#include <cstdint>
#include <cstddef>

#define DM 1024
#define HEADS 16
#define DHEAD 64
#define SEQ 2048
#define BATCH 2

typedef __bf16 bf16x8 __attribute__((ext_vector_type(8)));
typedef float  f32x4  __attribute__((ext_vector_type(4)));
typedef unsigned short u16;
typedef unsigned int u32;
typedef u16 u16x8 __attribute__((ext_vector_type(8)));
typedef u16 u16x4 __attribute__((ext_vector_type(4)));
typedef u32 u32x2 __attribute__((ext_vector_type(2)));

__device__ __forceinline__ float bf2f(u16 u){
    union { u32 i; float f; } v; v.i = ((u32)u) << 16; return v.f;
}
__device__ __forceinline__ u16 f2bf(float f){
    union { float f; u32 i; } v; v.f = f;
    u32 r = v.i + 0x7FFF + ((v.i >> 16) & 1);   // RNE
    return (u16)(r >> 16);
}
__device__ __forceinline__ u32 packbf2(float a, float b){  // round-half-up pack
    union { float f; u32 i; } x, y; x.f = a; y.f = b;
    return ((x.i + 0x8000u) >> 16) | ((y.i + 0x8000u) & 0xFFFF0000u);
}
__device__ __forceinline__ void gload16(const u16* g, u16* l){
    __builtin_amdgcn_global_load_lds(
        (const __attribute__((address_space(1))) u32*)g,
        (__attribute__((address_space(3))) u32*)l, 16, 0, 0);
}

// ---------------------------------------------------------------------------
// Probe: dtype flag (hdr[0]) + zero the 8 XCD work-claim counters (hdr[1..8]).
// ---------------------------------------------------------------------------
__global__ void k_probe(const u16* __restrict__ q, int* __restrict__ hdr){
    if (threadIdx.x == 0 && blockIdx.x == 0){
        int cnt = 0;
        for (int i = 0; i < 256; i += 2){
            int e = (q[i] >> 7) & 0xFF;
            if (e >= 90 && e <= 141) cnt++;
        }
        hdr[0] = (cnt >= 64) ? 1 : 0;
        #pragma unroll
        for (int c = 1; c <= 8; c++) hdr[c] = 0;
    }
}

// ---------------------------------------------------------------------------
// Convert 3 tensors (fp32|bf16) -> bf16, dst contiguous slots. z = tensor.
// ---------------------------------------------------------------------------
__global__ __launch_bounds__(256) void k_cvt3(const void* __restrict__ s0,
                                              const void* __restrict__ s1,
                                              const void* __restrict__ s2,
                                              u16* __restrict__ dstbase,
                                              const int* __restrict__ flag, int n){
    int z = blockIdx.y;
    const void* src = (z == 0) ? s0 : ((z == 1) ? s1 : s2);
    u16* dst = dstbase + (size_t)z * n;
    int i = (blockIdx.x * 256 + threadIdx.x) * 8;
    if (i >= n) return;
    if (*flag){
        *(u16x8*)&dst[i] = *(const u16x8*)((const u16*)src + i);
    } else {
        const float* s = (const float*)src + i;
        u16x8 o;
        #pragma unroll
        for (int j = 0; j < 8; j++) o[j] = f2bf(s[j]);
        *(u16x8*)&dst[i] = o;
    }
}

// ---------------------------------------------------------------------------
// Transpose+convert 4 weight matrices: dst_z[c][r] = cvt(src_z[r][c]).
// ---------------------------------------------------------------------------
__global__ void k_tcvt4(const void* __restrict__ w0, const void* __restrict__ w1,
                        const void* __restrict__ w2, const void* __restrict__ w3,
                        u16* __restrict__ dstbase,
                        const int* __restrict__ flag, int R, int C){
    __shared__ u16 tile[32][33];
    int z = blockIdx.z;
    const void* src = (z == 0) ? w0 : ((z == 1) ? w1 : ((z == 2) ? w2 : w3));
    u16* dst = dstbase + (size_t)z * R * C;
    bool isbf = (*flag != 0);
    int c0 = blockIdx.x * 32, r0 = blockIdx.y * 32;
    int tx = threadIdx.x, ty = threadIdx.y;     // 32 x 8
    #pragma unroll
    for (int i = 0; i < 32; i += 8){
        size_t idx = (size_t)(r0 + ty + i) * C + c0 + tx;
        tile[ty + i][tx] = isbf ? ((const u16*)src)[idx] : f2bf(((const float*)src)[idx]);
    }
    __syncthreads();
    #pragma unroll
    for (int i = 0; i < 32; i += 8)
        dst[(size_t)(c0 + ty + i) * R + r0 + tx] = tile[tx][ty + i];
}

// ---------------------------------------------------------------------------
// Plain bf16 batched transpose: dst[b][c][r] = src[b][r][c].
// ---------------------------------------------------------------------------
__global__ void k_transpose(const u16* __restrict__ src, u16* __restrict__ dst,
                            int R, int C){
    __shared__ u16 tile[32][33];
    size_t boff = (size_t)blockIdx.z * R * C;
    src += boff; dst += boff;
    int c0 = blockIdx.x * 32, r0 = blockIdx.y * 32;
    int tx = threadIdx.x, ty = threadIdx.y;
    #pragma unroll
    for (int i = 0; i < 32; i += 8)
        tile[ty + i][tx] = src[(size_t)(r0 + ty + i) * C + c0 + tx];
    __syncthreads();
    #pragma unroll
    for (int i = 0; i < 32; i += 8)
        dst[(size_t)(c0 + ty + i) * R + r0 + tx] = tile[tx][ty + i];
}

// ---------------------------------------------------------------------------
// C[M,N] = A[M,K]*Bt[N,K]^T, z-batched. 128x128 tile, BK=32, 4 waves,
// wave = 64x64 quadrant, global_load_lds(16B) into XOR-swizzled LDS.
// ---------------------------------------------------------------------------
__global__ __launch_bounds__(256, 2) void k_gemm3z(const u16* __restrict__ A0,
                                                   const u16* __restrict__ Bt0,
                                                   u16* __restrict__ C0,
                                                   size_t strA, size_t strB, size_t strC,
                                                   int M, int N, int K){
    __shared__ u16 lsA[128 * 32];   // row r, 16B-chunk c stored at slot c^(r&3)
    __shared__ u16 lsB[128 * 32];
    int z = blockIdx.z;
    const u16* A  = A0  + strA * z;
    const u16* Bt = Bt0 + strB * z;
    u16* C = C0 + strC * z;
    int m0 = blockIdx.y * 128, n0 = blockIdx.x * 128;
    int t = threadIdx.x, lane = t & 63, w = t >> 6;
    int l15 = lane & 15, quad = lane >> 4;
    int wm = (w & 1) * 64, wn = (w >> 1) * 64;
    int r0 = 32 * w + (lane >> 2);
    int r1 = r0 + 16;
    int c0s = (lane & 3) ^ (r0 & 3);
    int c1s = (lane & 3) ^ (r1 & 3);
    u16* dA0 = &lsA[(32 * w) * 32];       // wave-uniform LDS bases
    u16* dA1 = &lsA[(32 * w + 16) * 32];
    u16* dB0 = &lsB[(32 * w) * 32];
    u16* dB1 = &lsB[(32 * w + 16) * 32];
    f32x4 acc[4][4] = {};
    for (int k0 = 0; k0 < K; k0 += 32){
        __syncthreads();
        gload16(&A [(size_t)(m0 + r0) * K + k0 + c0s * 8], dA0);
        gload16(&A [(size_t)(m0 + r1) * K + k0 + c1s * 8], dA1);
        gload16(&Bt[(size_t)(n0 + r0) * K + k0 + c0s * 8], dB0);
        gload16(&Bt[(size_t)(n0 + r1) * K + k0 + c1s * 8], dB1);
        __syncthreads();
        bf16x8 af[4], bfr[4];
        #pragma unroll
        for (int i = 0; i < 4; i++){
            int row = wm + i * 16 + l15;
            af[i] = *(const bf16x8*)&lsA[row * 32 + ((quad ^ (row & 3)) * 8)];
        }
        #pragma unroll
        for (int j = 0; j < 4; j++){
            int row = wn + j * 16 + l15;
            bfr[j] = *(const bf16x8*)&lsB[row * 32 + ((quad ^ (row & 3)) * 8)];
        }
        #pragma unroll
        for (int i = 0; i < 4; i++)
            #pragma unroll
            for (int j = 0; j < 4; j++)
                acc[i][j] = __builtin_amdgcn_mfma_f32_16x16x32_bf16(af[i], bfr[j], acc[i][j], 0, 0, 0);
    }
    #pragma unroll
    for (int i = 0; i < 4; i++)
        #pragma unroll
        for (int j = 0; j < 4; j++)
            #pragma unroll
            for (int r = 0; r < 4; r++){
                int m = m0 + wm + i * 16 + quad * 4 + r;
                int n = n0 + wn + j * 16 + l15;
                C[(size_t)m * N + n] = f2bf(acc[i][j][r]);
            }
}

// ---------------------------------------------------------------------------
// Fused attention v6, softmax over HEADS.
// 512 blocks x 512 threads (8 waves; wave w owns heads w and w+8), qtile=32,
// ktile=32, nch k-split. 2 blocks/CU co-resident (72 KB LDS each) so the
// barrier phases of independent blocks overlap on the CU.
// Score MFMA operands swapped (A=K,B=Q -> D=S^T): C-layout rows = consecutive
// k for fixed q -> 4 exp'd scores pack into one ds_write_b64 in [q][k] layout.
// XCD work-claim: 8 combos x 64 slots; all blocks on an XCD stream the same
// 2MB K/V chunk (L2-resident).
// ---------------------------------------------------------------------------
__global__ __launch_bounds__(512, 4) void k_attn6(const u16* __restrict__ Qp,
                                                  const u16* __restrict__ Kp,
                                                  const u16* __restrict__ Vt,
                                                  u16* __restrict__ c0,
                                                  u16* __restrict__ c1,
                                                  u16* __restrict__ c2,
                                                  u16* __restrict__ c3,
                                                  int* __restrict__ cnt,
                                                  int ncomboM1, int iters, int capM1){
    __shared__ u16 ebuf[2][16][32][36];   // 72 KB; [buf][head][q][k(32)+pad]
    __shared__ int s_combo, s_slot;
    int t = threadIdx.x;
    if (t == 0){
        int xcc;
        asm volatile("s_getreg_b32 %0, hwreg(HW_REG_XCC_ID)" : "=s"(xcc));
        int start = xcc & ncomboM1;
        int combo = -1, slot = -1;
        for (int a = 0; a <= ncomboM1 && combo < 0; a++){
            int c = (start + a) & ncomboM1;
            int s = atomicAdd(&cnt[c], 1);
            if (s <= capM1){ combo = c; slot = s; }
        }
        s_combo = combo; s_slot = slot;
    }
    __syncthreads();
    int combo = s_combo;
    if (combo < 0) return;                 // unreachable; safety
    int b = combo & 1, chunk = combo >> 1;
    int q0 = s_slot * 32;
    int w = t >> 6, lane = t & 63, l15 = lane & 15, quad = lane >> 4;
    u16* outp = (chunk == 0) ? c0 : ((chunk == 1) ? c1 : ((chunk == 2) ? c2 : c3));
    const float cexp = 0.125f * 1.44269504f;
    int kbeg = chunk * (iters << 5);

    // wave w handles heads w and w+8
    bf16x8 qf[2][2][2];                    // [head][sub][ch]
    #pragma unroll
    for (int hd = 0; hd < 2; hd++){
        int h = w + hd * 8;
        #pragma unroll
        for (int sub = 0; sub < 2; sub++)
            #pragma unroll
            for (int ch = 0; ch < 2; ch++)
                qf[hd][sub][ch] = *(const bf16x8*)&Qp[((size_t)(b * SEQ + q0 + sub * 16 + l15)) * DM
                                                     + h * DHEAD + ch * 32 + quad * 8];
    }

    f32x4 oacc[2][2][4] = {};              // [head][sub][vt]
    int sq = t >> 4, sku = (t & 15) * 2;   // softmax owns (q=sq, k=sku..sku+1)

    auto score_phase = [&](int it){
        int k0 = kbeg + (it << 5), bf = it & 1;
        #pragma unroll
        for (int hd = 0; hd < 2; hd++){
            int h = w + hd * 8;
            #pragma unroll
            for (int kt = 0; kt < 2; kt++){
                const u16* kb = Kp + ((size_t)(b * SEQ + k0 + kt * 16 + l15)) * DM + h * DHEAD + quad * 8;
                bf16x8 kf0 = *(const bf16x8*)(kb);
                bf16x8 kf1 = *(const bf16x8*)(kb + 32);
                #pragma unroll
                for (int sub = 0; sub < 2; sub++){
                    // A=K, B=Q -> D rows = k-local (quad*4+r), cols = q-local (l15)
                    f32x4 sc = {};
                    sc = __builtin_amdgcn_mfma_f32_16x16x32_bf16(kf0, qf[hd][sub][0], sc, 0, 0, 0);
                    sc = __builtin_amdgcn_mfma_f32_16x16x32_bf16(kf1, qf[hd][sub][1], sc, 0, 0, 0);
                    float e0 = exp2f(sc[0] * cexp);
                    float e1 = exp2f(sc[1] * cexp);
                    float e2 = exp2f(sc[2] * cexp);
                    float e3 = exp2f(sc[3] * cexp);
                    u32x2 pk; pk[0] = packbf2(e0, e1); pk[1] = packbf2(e2, e3);
                    *(u32x2*)&ebuf[bf][h][sub * 16 + l15][kt * 16 + quad * 4] = pk;
                }
            }
        }
    };

    score_phase(0);
    for (int it = 0; it < iters; it++){
        int bf = it & 1;
        __syncthreads();                       // B1: e(it) complete
        {   // softmax across 16 heads, in place (u32 = 2 packed bf16)
            u32 ev[16];
            float s0 = 0.f, s1 = 0.f;
            #pragma unroll
            for (int hh = 0; hh < 16; hh++){
                u32 u = *(const u32*)&ebuf[bf][hh][sq][sku];
                ev[hh] = u;
                union { u32 i; float f; } lo, hi;
                lo.i = u << 16; hi.i = u & 0xFFFF0000u;
                s0 += lo.f; s1 += hi.f;
            }
            float r0 = __builtin_amdgcn_rcpf(s0);
            float r1 = __builtin_amdgcn_rcpf(s1);
            #pragma unroll
            for (int hh = 0; hh < 16; hh++){
                union { u32 i; float f; } lo, hi, p0, p1;
                lo.i = ev[hh] << 16; hi.i = ev[hh] & 0xFFFF0000u;
                p0.f = lo.f * r0; p1.f = hi.f * r1;
                *(u32*)&ebuf[bf][hh][sq][sku] =
                    ((p0.i + 0x8000u) >> 16) | ((p1.i + 0x8000u) & 0xFFFF0000u);
            }
        }
        __syncthreads();                       // B2: P(it) ready
        int k0 = kbeg + (it << 5);
        #pragma unroll
        for (int hd = 0; hd < 2; hd++){
            int h = w + hd * 8;
            bf16x8 pa[2];
            #pragma unroll
            for (int sub = 0; sub < 2; sub++){
                const u16* pp = &ebuf[bf][h][sub * 16 + l15][quad * 8];
                union { bf16x8 v; u16x4 q[2]; } pu;
                pu.q[0] = *(const u16x4*)pp;
                pu.q[1] = *(const u16x4*)(pp + 4);
                pa[sub] = pu.v;
            }
            #pragma unroll
            for (int vt = 0; vt < 4; vt++){
                bf16x8 vf = *(const bf16x8*)&Vt[((size_t)b * DM + h * DHEAD + vt * 16 + l15) * SEQ
                                                + k0 + quad * 8];
                oacc[hd][0][vt] = __builtin_amdgcn_mfma_f32_16x16x32_bf16(pa[0], vf, oacc[hd][0][vt], 0, 0, 0);
                oacc[hd][1][vt] = __builtin_amdgcn_mfma_f32_16x16x32_bf16(pa[1], vf, oacc[hd][1][vt], 0, 0, 0);
            }
        }
        if (it + 1 < iters) score_phase(it + 1);
    }
    #pragma unroll
    for (int hd = 0; hd < 2; hd++){
        int h = w + hd * 8;
        #pragma unroll
        for (int sub = 0; sub < 2; sub++)
            #pragma unroll
            for (int vt = 0; vt < 4; vt++)
                #pragma unroll
                for (int r = 0; r < 4; r++){
                    int q = q0 + sub * 16 + quad * 4 + r;
                    int n = h * DHEAD + vt * 16 + l15;
                    outp[((size_t)b * SEQ + q) * DM + n] = f2bf(oacc[hd][sub][vt][r]);
                }
    }
}

// ---------------------------------------------------------------------------
// dst = c0+c1(+c2+c3) (bf16). dst may alias c0 (same-index load-then-store).
// ---------------------------------------------------------------------------
__global__ __launch_bounds__(256) void k_reduce(const u16* __restrict__ a,
                                                const u16* __restrict__ b,
                                                const u16* __restrict__ c,
                                                const u16* __restrict__ d,
                                                u16* __restrict__ dst, int n, int nch){
    int i = (blockIdx.x * 256 + threadIdx.x) * 8;
    if (i >= n) return;
    u16x8 x = *(const u16x8*)&a[i];
    u16x8 y = *(const u16x8*)&b[i];
    u16x8 o;
    if (nch == 4){
        u16x8 zc = *(const u16x8*)&c[i];
        u16x8 zd = *(const u16x8*)&d[i];
        #pragma unroll
        for (int j = 0; j < 8; j++)
            o[j] = f2bf((bf2f(x[j]) + bf2f(y[j])) + (bf2f(zc[j]) + bf2f(zd[j])));
    } else {
        #pragma unroll
        for (int j = 0; j < 8; j++) o[j] = f2bf(bf2f(x[j]) + bf2f(y[j]));
    }
    *(u16x8*)&dst[i] = o;
}

// ---------------------------------------------------------------------------
// Residual + LayerNorm over last dim (1024). One block per row.
// ---------------------------------------------------------------------------
__global__ __launch_bounds__(256) void k_ln(const u16* __restrict__ O,
                                            const void* __restrict__ Qin,
                                            const void* __restrict__ gamma,
                                            const void* __restrict__ beta,
                                            void* __restrict__ out,
                                            const int* __restrict__ flag){
    __shared__ float red[4][2];
    bool isbf = (*flag != 0);
    int row = blockIdx.x;
    int t = threadIdx.x;
    const u16* op = O + (size_t)row * DM;
    float xv[4];
    float s1 = 0.f, s2 = 0.f;
    #pragma unroll
    for (int i = 0; i < 4; i++){
        int idx = i * 256 + t;
        float q = isbf ? bf2f(((const u16*)Qin)[(size_t)row * DM + idx])
                       : ((const float*)Qin)[(size_t)row * DM + idx];
        float x = bf2f(op[idx]) + q;
        xv[i] = x; s1 += x; s2 += x * x;
    }
    #pragma unroll
    for (int off = 32; off; off >>= 1){
        s1 += __shfl_down(s1, off);
        s2 += __shfl_down(s2, off);
    }
    int w = t >> 6, lane = t & 63;
    if (lane == 0){ red[w][0] = s1; red[w][1] = s2; }
    __syncthreads();
    float S1 = red[0][0] + red[1][0] + red[2][0] + red[3][0];
    float S2 = red[0][1] + red[1][1] + red[2][1] + red[3][1];
    float mu  = S1 * (1.0f / DM);
    float var = S2 * (1.0f / DM) - mu * mu;
    float rstd = rsqrtf(var + 1e-5f);
    #pragma unroll
    for (int i = 0; i < 4; i++){
        int idx = i * 256 + t;
        float g = isbf ? bf2f(((const u16*)gamma)[idx]) : ((const float*)gamma)[idx];
        float bb= isbf ? bf2f(((const u16*)beta )[idx]) : ((const float*)beta )[idx];
        float y = (xv[i] - mu) * rstd * g + bb;
        if (isbf) ((u16*)out)[(size_t)row * DM + idx] = f2bf(y);
        else      ((float*)out)[(size_t)row * DM + idx] = y;
    }
}

// ---------------------------------------------------------------------------
extern "C" void kernel_launch(void* const* d_in, const int* in_sizes, int n_in,
                              void* d_out, int out_size, void* d_ws, size_t ws_size,
                              hipStream_t stream){
    (void)in_sizes; (void)n_in; (void)out_size;
    const void* inQ = d_in[0];
    const void* inK = d_in[1];
    const void* inV = d_in[2];
    const void* wQ  = d_in[3];
    const void* wK  = d_in[4];
    const void* wV  = d_in[5];
    const void* wO  = d_in[6];
    const void* gma = d_in[7];
    const void* bta = d_in[8];

    int* hdr  = (int*)d_ws;                    // [0]=flag, [1..8]=claim counters
    int* flag = hdr;
    int* cnt  = hdr + 1;
    u16* base = (u16*)d_ws + 64;               // 128 B header

    const size_t MB1 = 1024u * 1024u;          // elements
    const size_t M4  = 4u * MB1;
    u16* Qi  = base + 0;                       // slot0: bf16 Q input -> ctxp0/cx
    u16* Ki  = base + 1 * M4;                  // slot1: bf16 K input -> Vt
    u16* Vi  = base + 2 * M4;                  // slot2: bf16 V input -> ctxp2
    u16* WtQ = base + 3 * M4;                  // slot3: 4 x W^T [1024,1024]
    u16* WtO = WtQ + 3 * MB1;
    u16* Qp  = base + 4 * M4;                  // slot4: Q proj -> Ob
    u16* Kp  = base + 5 * M4;                  // slot5: K proj
    u16* Vp  = base + 6 * M4;                  // slot6: V proj -> ctxp1
    u16* ext = base + 7 * M4;                  // slot7: ctxp3 (if ws allows)
    u16* Vt    = Ki;
    u16* ctxp0 = Qi;
    u16* ctxp1 = Vp;
    u16* ctxp2 = Vi;

    size_t need4 = 128 + 8 * M4 * sizeof(u16);
    int nch = (ws_size >= need4) ? 4 : 2;
    u16* ctxp3 = (nch == 4) ? ext : ctxp2;     // dummy when nch==2 (never selected)
    int ncomboM1 = 2 * nch - 1;
    int iters   = (nch == 4) ? 16 : 32;        // keys per chunk / 32
    int ablocks = 64 * 2 * nch;                // 64 qtiles * 2 b * nch chunks
    int capM1   = 63;                          // 64 qtile slots per combo

    k_probe<<<1, 64, 0, stream>>>((const u16*)inQ, hdr);

    const int nIn = BATCH * SEQ * DM;          // 4M
    k_cvt3<<<dim3(nIn / 2048, 3), 256, 0, stream>>>(inQ, inK, inV, base, flag, nIn);

    k_tcvt4<<<dim3(32, 32, 4), dim3(32, 8), 0, stream>>>(wQ, wK, wV, wO, WtQ, flag, 1024, 1024);

    // Q/K/V projections in one dispatch (z selects A/Bt/C triple)
    k_gemm3z<<<dim3(8, 32, 3), 256, 0, stream>>>(Qi, WtQ, Qp, M4, MB1, M4, 4096, 1024, 1024);

    k_transpose<<<dim3(32, 64, 2), dim3(32, 8), 0, stream>>>(Vp, Vt, 2048, 1024);

    k_attn6<<<ablocks, 512, 0, stream>>>(Qp, Kp, Vt, ctxp0, ctxp1, ctxp2, ctxp3,
                                         cnt, ncomboM1, iters, capM1);

    k_reduce<<<nIn / 2048, 256, 0, stream>>>(ctxp0, ctxp1, ctxp2, ctxp3, ctxp0, nIn, nch);

    k_gemm3z<<<dim3(8, 32, 1), 256, 0, stream>>>(ctxp0, WtO, Qp, 0, 0, 0, 4096, 1024, 1024);

    k_ln<<<4096, 256, 0, stream>>>(Qp, inQ, gma, bta, d_out, flag);
}

// Round 10
// 347.345 us; speedup vs baseline: 1.1274x; 1.1274x over previous
//
#include <hip/hip_runtime.h>
#include <cstdint>
#include <cstddef>

#define DM 1024
#define HEADS 16
#define DHEAD 64
#define SEQ 2048
#define BATCH 2

typedef __bf16 bf16x8 __attribute__((ext_vector_type(8)));
typedef float  f32x4  __attribute__((ext_vector_type(4)));
typedef unsigned short u16;
typedef unsigned int u32;
typedef u16 u16x8 __attribute__((ext_vector_type(8)));
typedef u16 u16x4 __attribute__((ext_vector_type(4)));
typedef u32 u32x2 __attribute__((ext_vector_type(2)));

__device__ __forceinline__ float bf2f(u16 u){
    union { u32 i; float f; } v; v.i = ((u32)u) << 16; return v.f;
}
__device__ __forceinline__ u16 f2bf(float f){
    union { float f; u32 i; } v; v.f = f;
    u32 r = v.i + 0x7FFF + ((v.i >> 16) & 1);   // RNE
    return (u16)(r >> 16);
}
__device__ __forceinline__ u32 packbf2(float a, float b){  // round-half-up pack
    union { float f; u32 i; } x, y; x.f = a; y.f = b;
    return ((x.i + 0x8000u) >> 16) | ((y.i + 0x8000u) & 0xFFFF0000u);
}
__device__ __forceinline__ void gload16(const u16* g, u16* l){
    __builtin_amdgcn_global_load_lds(
        (const __attribute__((address_space(1))) u32*)g,
        (__attribute__((address_space(3))) u32*)l, 16, 0, 0);
}

// ---------------------------------------------------------------------------
// Probe: dtype flag only (hdr[0]).
// ---------------------------------------------------------------------------
__global__ void k_probe(const u16* __restrict__ q, int* __restrict__ hdr){
    if (threadIdx.x == 0 && blockIdx.x == 0){
        int cnt = 0;
        for (int i = 0; i < 256; i += 2){
            int e = (q[i] >> 7) & 0xFF;
            if (e >= 90 && e <= 141) cnt++;
        }
        hdr[0] = (cnt >= 64) ? 1 : 0;
    }
}

// ---------------------------------------------------------------------------
// Fused prep: blocks [0,6144): convert Q/K/V inputs -> bf16 slots 0..2.
//             blocks [6144,10240): transpose+convert 4 weights -> WtQ..WtO.
//             block 0 additionally zeroes the 8 XCD claim counters.
// ---------------------------------------------------------------------------
__global__ __launch_bounds__(256) void k_prep(const void* __restrict__ iQ,
                                              const void* __restrict__ iK,
                                              const void* __restrict__ iV,
                                              const void* __restrict__ w0,
                                              const void* __restrict__ w1,
                                              const void* __restrict__ w2,
                                              const void* __restrict__ w3,
                                              u16* __restrict__ base,
                                              u16* __restrict__ wtbase,
                                              int* __restrict__ hdr, int nIn){
    __shared__ u16 tile[32][33];
    int bid = blockIdx.x, t = threadIdx.x;
    bool isbf = (hdr[0] != 0);
    if (bid == 0 && t < 8) hdr[1 + t] = 0;   // claim counters for k_attn
    if (bid < 6144){
        int z = bid >> 11;                   // 2048 blocks per tensor
        const void* src = (z == 0) ? iQ : ((z == 1) ? iK : iV);
        u16* dst = base + (size_t)z * nIn;
        int i = ((bid & 2047) * 256 + t) * 8;
        if (isbf){
            *(u16x8*)&dst[i] = *(const u16x8*)((const u16*)src + i);
        } else {
            const float* s = (const float*)src + i;
            u16x8 o;
            #pragma unroll
            for (int j = 0; j < 8; j++) o[j] = f2bf(s[j]);
            *(u16x8*)&dst[i] = o;
        }
    } else {
        int bid2 = bid - 6144;
        int z = bid2 >> 10, tl = bid2 & 1023;
        const void* src = (z == 0) ? w0 : ((z == 1) ? w1 : ((z == 2) ? w2 : w3));
        u16* dst = wtbase + (size_t)z * DM * DM;
        int c0 = (tl & 31) * 32, r0 = (tl >> 5) * 32;
        int tx = t & 31, ty = t >> 5;        // 32 x 8
        #pragma unroll
        for (int i = 0; i < 32; i += 8){
            size_t idx = (size_t)(r0 + ty + i) * DM + c0 + tx;
            tile[ty + i][tx] = isbf ? ((const u16*)src)[idx] : f2bf(((const float*)src)[idx]);
        }
        __syncthreads();
        #pragma unroll
        for (int i = 0; i < 32; i += 8)
            dst[(size_t)(c0 + ty + i) * DM + r0 + tx] = tile[tx][ty + i];
    }
}

// ---------------------------------------------------------------------------
// C = A[M,K]*Bt[N,K]^T, z-batched. 128x128 tile, BK=32, 4 waves, wave=64x64
// quadrant, 16B global_load_lds into XOR-swizzled LDS.
// z selects (A, C); Bt = Bt0 + z*strB. M fixed at 4096, N at 1024 (DM).
// If vtrans && z==2: write C transposed as Vt[b][n][s] (s = m & 2047).
// ---------------------------------------------------------------------------
__global__ __launch_bounds__(256, 2) void k_gemm3z(const u16* __restrict__ A0,
                                                   const u16* __restrict__ Bt0,
                                                   u16* __restrict__ Cq,
                                                   u16* __restrict__ Ck,
                                                   u16* __restrict__ Cv,
                                                   size_t strA, size_t strB,
                                                   int K, int vtrans){
    __shared__ u16 lsA[128 * 32];   // row r, 16B-chunk c stored at slot c^(r&3)
    __shared__ u16 lsB[128 * 32];
    int z = blockIdx.z;
    const u16* A  = A0  + strA * z;
    const u16* Bt = Bt0 + strB * z;
    u16* C = (z == 0) ? Cq : ((z == 1) ? Ck : Cv);
    int m0 = blockIdx.y * 128, n0 = blockIdx.x * 128;
    int t = threadIdx.x, lane = t & 63, w = t >> 6;
    int l15 = lane & 15, quad = lane >> 4;
    int wm = (w & 1) * 64, wn = (w >> 1) * 64;
    int r0 = 32 * w + (lane >> 2);
    int r1 = r0 + 16;
    int c0s = (lane & 3) ^ (r0 & 3);
    int c1s = (lane & 3) ^ (r1 & 3);
    u16* dA0 = &lsA[(32 * w) * 32];       // wave-uniform LDS bases
    u16* dA1 = &lsA[(32 * w + 16) * 32];
    u16* dB0 = &lsB[(32 * w) * 32];
    u16* dB1 = &lsB[(32 * w + 16) * 32];
    f32x4 acc[4][4] = {};
    for (int k0 = 0; k0 < K; k0 += 32){
        __syncthreads();
        gload16(&A [(size_t)(m0 + r0) * K + k0 + c0s * 8], dA0);
        gload16(&A [(size_t)(m0 + r1) * K + k0 + c1s * 8], dA1);
        gload16(&Bt[(size_t)(n0 + r0) * K + k0 + c0s * 8], dB0);
        gload16(&Bt[(size_t)(n0 + r1) * K + k0 + c1s * 8], dB1);
        __syncthreads();
        bf16x8 af[4], bfr[4];
        #pragma unroll
        for (int i = 0; i < 4; i++){
            int row = wm + i * 16 + l15;
            af[i] = *(const bf16x8*)&lsA[row * 32 + ((quad ^ (row & 3)) * 8)];
        }
        #pragma unroll
        for (int j = 0; j < 4; j++){
            int row = wn + j * 16 + l15;
            bfr[j] = *(const bf16x8*)&lsB[row * 32 + ((quad ^ (row & 3)) * 8)];
        }
        #pragma unroll
        for (int i = 0; i < 4; i++)
            #pragma unroll
            for (int j = 0; j < 4; j++)
                acc[i][j] = __builtin_amdgcn_mfma_f32_16x16x32_bf16(af[i], bfr[j], acc[i][j], 0, 0, 0);
    }
    if (vtrans && z == 2){
        // Vt[b][n][s]: b = m>>11, s = m&2047; 4 consecutive m -> one 8B store
        #pragma unroll
        for (int i = 0; i < 4; i++){
            int m = m0 + wm + i * 16 + quad * 4;
            int bb = m >> 11, s = m & 2047;
            #pragma unroll
            for (int j = 0; j < 4; j++){
                int n = n0 + wn + j * 16 + l15;
                u16x4 o;
                #pragma unroll
                for (int r = 0; r < 4; r++) o[r] = f2bf(acc[i][j][r]);
                *(u16x4*)&C[((size_t)bb * DM + n) * SEQ + s] = o;
            }
        }
    } else {
        #pragma unroll
        for (int i = 0; i < 4; i++)
            #pragma unroll
            for (int j = 0; j < 4; j++)
                #pragma unroll
                for (int r = 0; r < 4; r++){
                    int m = m0 + wm + i * 16 + quad * 4 + r;
                    int n = n0 + wn + j * 16 + l15;
                    C[(size_t)m * DM + n] = f2bf(acc[i][j][r]);
                }
    }
}

// ---------------------------------------------------------------------------
// Fused attention v7, softmax over HEADS. qtile=64, ktile=32, nch k-split,
// 1024 threads = 16 waves (wave h = head h). Double-buffered e/P LDS.
// Score MFMA operands swapped (A=K, B=Q -> D holds S^T): 4 exp'd scores for
// consecutive k pack into one 8B LDS write in [q][k] layout (R7-verified).
// XCD work-claim (R6): blocks on one XCD stream the same 2MB K/V chunk.
// ---------------------------------------------------------------------------
__global__ __launch_bounds__(1024, 4) void k_attn7(const u16* __restrict__ Qp,
                                                   const u16* __restrict__ Kp,
                                                   const u16* __restrict__ Vt,
                                                   u16* __restrict__ c0,
                                                   u16* __restrict__ c1,
                                                   u16* __restrict__ c2,
                                                   u16* __restrict__ c3,
                                                   int* __restrict__ cnt,
                                                   int ncomboM1, int iters){
    __shared__ u16 ebuf[2][16][64][36];   // 144 KB; [buf][head][q][k(32)+pad]
    __shared__ int s_combo, s_slot;
    int t = threadIdx.x;
    if (t == 0){
        int xcc;
        asm volatile("s_getreg_b32 %0, hwreg(HW_REG_XCC_ID)" : "=s"(xcc));
        int start = xcc & ncomboM1;
        int combo = -1, slot = -1;
        for (int a = 0; a <= ncomboM1 && combo < 0; a++){
            int c = (start + a) & ncomboM1;
            int s = atomicAdd(&cnt[c], 1);
            if (s < 32){ combo = c; slot = s; }
        }
        s_combo = combo; s_slot = slot;
    }
    __syncthreads();
    int combo = s_combo;
    if (combo < 0) return;
    int b = combo & 1, chunk = combo >> 1;
    int q0 = s_slot * 64;
    int h = t >> 6, lane = t & 63, l15 = lane & 15, quad = lane >> 4;
    u16* outp = (chunk == 0) ? c0 : ((chunk == 1) ? c1 : ((chunk == 2) ? c2 : c3));
    const float cexp = 0.125f * 1.44269504f;
    int kbeg = chunk * (iters << 5);

    bf16x8 qf[4][2];
    #pragma unroll
    for (int sub = 0; sub < 4; sub++)
        #pragma unroll
        for (int ch = 0; ch < 2; ch++)
            qf[sub][ch] = *(const bf16x8*)&Qp[((size_t)(b * SEQ + q0 + sub * 16 + l15)) * DM
                                             + h * DHEAD + ch * 32 + quad * 8];

    f32x4 oacc[4][4] = {};
    int sq = t >> 4, sku = (t & 15) * 2;   // softmax owns (q=sq, k=sku..sku+1)

    auto score_phase = [&](int it){
        int k0 = kbeg + (it << 5), bf = it & 1;
        #pragma unroll
        for (int kt = 0; kt < 2; kt++){
            const u16* kb = Kp + ((size_t)(b * SEQ + k0 + kt * 16 + l15)) * DM + h * DHEAD + quad * 8;
            bf16x8 kf0 = *(const bf16x8*)(kb);
            bf16x8 kf1 = *(const bf16x8*)(kb + 32);
            #pragma unroll
            for (int sub = 0; sub < 4; sub++){
                // A=K, B=Q -> D rows = k-local (quad*4+r), cols = q-local (l15)
                f32x4 sc = {};
                sc = __builtin_amdgcn_mfma_f32_16x16x32_bf16(kf0, qf[sub][0], sc, 0, 0, 0);
                sc = __builtin_amdgcn_mfma_f32_16x16x32_bf16(kf1, qf[sub][1], sc, 0, 0, 0);
                u32x2 pk;
                pk[0] = packbf2(exp2f(sc[0] * cexp), exp2f(sc[1] * cexp));
                pk[1] = packbf2(exp2f(sc[2] * cexp), exp2f(sc[3] * cexp));
                *(u32x2*)&ebuf[bf][h][sub * 16 + l15][kt * 16 + quad * 4] = pk;
            }
        }
    };

    score_phase(0);
    for (int it = 0; it < iters; it++){
        int bf = it & 1;
        __syncthreads();                       // B1: e(it) complete
        {   // softmax across 16 heads, in place (u32 = 2 packed bf16)
            u32 ev[16];
            float s0 = 0.f, s1 = 0.f;
            #pragma unroll
            for (int hh = 0; hh < 16; hh++){
                u32 u = *(const u32*)&ebuf[bf][hh][sq][sku];
                ev[hh] = u;
                union { u32 i; float f; } lo, hi;
                lo.i = u << 16; hi.i = u & 0xFFFF0000u;
                s0 += lo.f; s1 += hi.f;
            }
            float r0 = __builtin_amdgcn_rcpf(s0);
            float r1 = __builtin_amdgcn_rcpf(s1);
            #pragma unroll
            for (int hh = 0; hh < 16; hh++){
                union { u32 i; float f; } lo, hi, p0, p1;
                lo.i = ev[hh] << 16; hi.i = ev[hh] & 0xFFFF0000u;
                p0.f = lo.f * r0; p1.f = hi.f * r1;
                *(u32*)&ebuf[bf][hh][sq][sku] =
                    ((p0.i + 0x8000u) >> 16) | ((p1.i + 0x8000u) & 0xFFFF0000u);
            }
        }
        __syncthreads();                       // B2: P(it) ready
        int k0 = kbeg + (it << 5);
        bf16x8 pa[4];
        #pragma unroll
        for (int sub = 0; sub < 4; sub++){
            const u16* pp = &ebuf[bf][h][sub * 16 + l15][quad * 8];
            union { bf16x8 v; u16x4 q[2]; } pu;
            pu.q[0] = *(const u16x4*)pp;
            pu.q[1] = *(const u16x4*)(pp + 4);
            pa[sub] = pu.v;
        }
        #pragma unroll
        for (int vt = 0; vt < 4; vt++){
            bf16x8 vf = *(const bf16x8*)&Vt[((size_t)b * DM + h * DHEAD + vt * 16 + l15) * SEQ
                                            + k0 + quad * 8];
            #pragma unroll
            for (int sub = 0; sub < 4; sub++)
                oacc[sub][vt] = __builtin_amdgcn_mfma_f32_16x16x32_bf16(pa[sub], vf, oacc[sub][vt], 0, 0, 0);
        }
        if (it + 1 < iters) score_phase(it + 1);
    }
    #pragma unroll
    for (int sub = 0; sub < 4; sub++)
        #pragma unroll
        for (int vt = 0; vt < 4; vt++)
            #pragma unroll
            for (int r = 0; r < 4; r++){
                int q = q0 + sub * 16 + quad * 4 + r;
                int n = h * DHEAD + vt * 16 + l15;
                outp[((size_t)b * SEQ + q) * DM + n] = f2bf(oacc[sub][vt][r]);
            }
}

// ---------------------------------------------------------------------------
// dst = c0+c1(+c2+c3) (bf16). dst may alias c0 (same-index load-then-store).
// ---------------------------------------------------------------------------
__global__ __launch_bounds__(256) void k_reduce(const u16* __restrict__ a,
                                                const u16* __restrict__ b,
                                                const u16* __restrict__ c,
                                                const u16* __restrict__ d,
                                                u16* __restrict__ dst, int n, int nch){
    int i = (blockIdx.x * 256 + threadIdx.x) * 8;
    if (i >= n) return;
    u16x8 x = *(const u16x8*)&a[i];
    u16x8 y = *(const u16x8*)&b[i];
    u16x8 o;
    if (nch == 4){
        u16x8 zc = *(const u16x8*)&c[i];
        u16x8 zd = *(const u16x8*)&d[i];
        #pragma unroll
        for (int j = 0; j < 8; j++)
            o[j] = f2bf((bf2f(x[j]) + bf2f(y[j])) + (bf2f(zc[j]) + bf2f(zd[j])));
    } else {
        #pragma unroll
        for (int j = 0; j < 8; j++) o[j] = f2bf(bf2f(x[j]) + bf2f(y[j]));
    }
    *(u16x8*)&dst[i] = o;
}

// ---------------------------------------------------------------------------
// Residual + LayerNorm over last dim (1024). One block per row.
// ---------------------------------------------------------------------------
__global__ __launch_bounds__(256) void k_ln(const u16* __restrict__ O,
                                            const void* __restrict__ Qin,
                                            const void* __restrict__ gamma,
                                            const void* __restrict__ beta,
                                            void* __restrict__ out,
                                            const int* __restrict__ flag){
    __shared__ float red[4][2];
    bool isbf = (*flag != 0);
    int row = blockIdx.x;
    int t = threadIdx.x;
    const u16* op = O + (size_t)row * DM;
    float xv[4];
    float s1 = 0.f, s2 = 0.f;
    #pragma unroll
    for (int i = 0; i < 4; i++){
        int idx = i * 256 + t;
        float q = isbf ? bf2f(((const u16*)Qin)[(size_t)row * DM + idx])
                       : ((const float*)Qin)[(size_t)row * DM + idx];
        float x = bf2f(op[idx]) + q;
        xv[i] = x; s1 += x; s2 += x * x;
    }
    #pragma unroll
    for (int off = 32; off; off >>= 1){
        s1 += __shfl_down(s1, off);
        s2 += __shfl_down(s2, off);
    }
    int w = t >> 6, lane = t & 63;
    if (lane == 0){ red[w][0] = s1; red[w][1] = s2; }
    __syncthreads();
    float S1 = red[0][0] + red[1][0] + red[2][0] + red[3][0];
    float S2 = red[0][1] + red[1][1] + red[2][1] + red[3][1];
    float mu  = S1 * (1.0f / DM);
    float var = S2 * (1.0f / DM) - mu * mu;
    float rstd = rsqrtf(var + 1e-5f);
    #pragma unroll
    for (int i = 0; i < 4; i++){
        int idx = i * 256 + t;
        float g = isbf ? bf2f(((const u16*)gamma)[idx]) : ((const float*)gamma)[idx];
        float bb= isbf ? bf2f(((const u16*)beta )[idx]) : ((const float*)beta )[idx];
        float y = (xv[i] - mu) * rstd * g + bb;
        if (isbf) ((u16*)out)[(size_t)row * DM + idx] = f2bf(y);
        else      ((float*)out)[(size_t)row * DM + idx] = y;
    }
}

// ---------------------------------------------------------------------------
extern "C" void kernel_launch(void* const* d_in, const int* in_sizes, int n_in,
                              void* d_out, int out_size, void* d_ws, size_t ws_size,
                              hipStream_t stream){
    (void)in_sizes; (void)n_in; (void)out_size;
    const void* inQ = d_in[0];
    const void* inK = d_in[1];
    const void* inV = d_in[2];
    const void* wQ  = d_in[3];
    const void* wK  = d_in[4];
    const void* wV  = d_in[5];
    const void* wO  = d_in[6];
    const void* gma = d_in[7];
    const void* bta = d_in[8];

    int* hdr  = (int*)d_ws;                    // [0]=flag, [1..8]=claim counters
    int* flag = hdr;
    int* cnt  = hdr + 1;
    u16* base = (u16*)d_ws + 64;               // 128 B header

    const size_t MB1 = 1024u * 1024u;          // elements
    const size_t M4  = 4u * MB1;
    u16* Qi  = base + 0;                       // slot0: bf16 Q input -> ctxp0/cx
    u16* Ki  = base + 1 * M4;                  // slot1: bf16 K input -> ctxp1
    u16* Vi  = base + 2 * M4;                  // slot2: bf16 V input -> ctxp2
    u16* WtQ = base + 3 * M4;                  // slot3: 4 x W^T [1024,1024]
    u16* WtO = WtQ + 3 * MB1;
    u16* Qp  = base + 4 * M4;                  // slot4: Q proj -> Ob
    u16* Kp  = base + 5 * M4;                  // slot5: K proj
    u16* Vt  = base + 6 * M4;                  // slot6: Vt [2][1024][2048] (direct)
    u16* ext = base + 7 * M4;                  // slot7: ctxp3 (if ws allows)
    u16* ctxp0 = Qi;
    u16* ctxp1 = Ki;
    u16* ctxp2 = Vi;

    size_t need4 = 128 + 8 * M4 * sizeof(u16);
    int nch = (ws_size >= need4) ? 4 : 2;
    u16* ctxp3 = (nch == 4) ? ext : ctxp2;     // dummy when nch==2 (never selected)
    int ncomboM1 = 2 * nch - 1;
    int iters   = (nch == 4) ? 16 : 32;        // keys per chunk / 32
    int ablocks = 32 * 2 * nch;

    k_probe<<<1, 64, 0, stream>>>((const u16*)inQ, hdr);

    const int nIn = BATCH * SEQ * DM;          // 4M
    k_prep<<<10240, 256, 0, stream>>>(inQ, inK, inV, wQ, wK, wV, wO,
                                      base, WtQ, hdr, nIn);

    // Q/K/V projections in one dispatch; V written directly transposed to Vt
    k_gemm3z<<<dim3(8, 32, 3), 256, 0, stream>>>(Qi, WtQ, Qp, Kp, Vt,
                                                 M4, MB1, 1024, 1);

    k_attn7<<<ablocks, 1024, 0, stream>>>(Qp, Kp, Vt, ctxp0, ctxp1, ctxp2, ctxp3,
                                          cnt, ncomboM1, iters);

    k_reduce<<<nIn / 2048, 256, 0, stream>>>(ctxp0, ctxp1, ctxp2, ctxp3, ctxp0, nIn, nch);

    // O projection (z grid = 1, Bt = WtO, C = Qp reused as Ob)
    k_gemm3z<<<dim3(8, 32, 1), 256, 0, stream>>>(ctxp0, WtO, Qp, Qp, Qp,
                                                 0, 0, 1024, 0);

    k_ln<<<4096, 256, 0, stream>>>(Qp, inQ, gma, bta, d_out, flag);
}